// Round 4
// baseline (499.475 us; speedup 1.0000x reference)
//
#include <hip/hip_runtime.h>
#include <stdint.h>
#include <stddef.h>

#define D_MODEL 1024
#define SEQ     4096
#define BATCH   4
#define MTOT    (BATCH*SEQ)     // 16384
#define NWIN    63

typedef __bf16 bf16;
typedef __bf16 bf16x8 __attribute__((ext_vector_type(8)));
typedef __bf16 bf16x4 __attribute__((ext_vector_type(4)));
typedef float  floatx4 __attribute__((ext_vector_type(4)));

// async global->LDS, 16B per lane. LDS dest must be wave-uniform base + lane*16.
__device__ __forceinline__ void async_ld16(const void* g, void* l) {
  __builtin_amdgcn_global_load_lds(
      (const __attribute__((address_space(1))) unsigned int*)g,
      (__attribute__((address_space(3))) unsigned int*)l,
      16, 0, 0);
}

// ---------------- elementwise converts ----------------

__global__ __launch_bounds__(256)
void cvt_x_kernel(const float* __restrict__ x, bf16* __restrict__ xb)
{
  const int i = blockIdx.x * 256 + threadIdx.x;   // exactly 4M threads (16M elems /4)
  const float4 v = ((const float4*)x)[i];
  bf16x4 o = { (bf16)v.x, (bf16)v.y, (bf16)v.z, (bf16)v.w };
  ((bf16x4*)xb)[i] = o;
}

// W (fp32, [K][N]) -> Wt (bf16, [N][K]), packed: rows 0..1023=Wq^T, ..., 3072..4095=Wo^T
__global__ __launch_bounds__(256)
void cvt_wt_kernel(const float* __restrict__ W0, const float* __restrict__ W1,
                   const float* __restrict__ W2, const float* __restrict__ W3,
                   bf16* __restrict__ wt)
{
  __shared__ float tile[32][33];
  const float* Wsel = (blockIdx.z == 0) ? W0 : (blockIdx.z == 1) ? W1
                    : (blockIdx.z == 2) ? W2 : W3;
  bf16* Wt = wt + (size_t)blockIdx.z * D_MODEL * D_MODEL;
  const int tx = threadIdx.x & 31, ty = threadIdx.x >> 5;  // 32 x 8
  const int tn = blockIdx.x * 32, tk = blockIdx.y * 32;
#pragma unroll
  for (int j = 0; j < 32; j += 8)
    tile[ty + j][tx] = Wsel[(size_t)(tk + ty + j) * D_MODEL + (tn + tx)];
  __syncthreads();
#pragma unroll
  for (int j = 0; j < 32; j += 8)
    Wt[(size_t)(tn + ty + j) * D_MODEL + (tk + tx)] = (bf16)tile[tx][ty + j];
}

// ---------------- GEMM core: 256x256 tile, BK=32, 2-phase triple-buffered -------
// 8 waves (2M x 4N), 512 threads. Per wave: 128x64 output = acc[8][4].
// LDS: A,B each TRIPLE-buffered 16KB (96KB total; 16 frags x 512 elem per buffer).
// Staging runs 2 K-tiles ahead. Per K-tile t (BK=32): 2 phases of 16 MFMA. Phase p:
//   issue 1 A-load + 1 B-load of tile t+2, unit p  -> buf[(t+2)%3]
//   ds_read_b128: p0 reads B-full (4) + A half (4) = 8; p1 reads A half (4)
//   s_barrier ; lgkmcnt(0) ; setprio(1) ; 16 MFMA ; setprio(0)
//   [p1 only: s_waitcnt vmcnt(4)  <- tile t+1 landed, t+2's 4 stay in flight]
//   s_barrier
// vmcnt never drains below 4 in steady state (T4). B-frags held in regs across
// phases. Frag-contiguous LDS layout is conflict-free (lane l reads frag*1KB+l*16B).
__device__ __forceinline__ void gemm_core_3b(const bf16* __restrict__ A,
                                             const bf16* __restrict__ Bt,
                                             int m0, int n0,
                                             bf16* As, bf16* Bs,
                                             floatx4 (&acc)[8][4],
                                             int w, int l)
{
  const int ll = l & 15, lh = l >> 4;
  const int wm = w >> 2, wn = w & 3;
  const bf16* Ab = A  + (size_t)(m0 + ll) * D_MODEL + lh * 8;
  const bf16* Bb = Bt + (size_t)(n0 + ll) * D_MODEL + lh * 8;

  // stage unit u (0..1) of K-tile t into buffer b: wave w stages frag f=u*8+w.
  // frag f (0..15): rows f*16..f*16+15, cols k0..k0+31 of the 256x32 tile.
  auto stage_unit = [&](int t, int u, int b) {
    const int k0 = t << 5;
    const int f = u * 8 + w;
    async_ld16(Ab + (size_t)(f * 16) * D_MODEL + k0, As + b * 8192 + f * 512 + l * 8);
    async_ld16(Bb + (size_t)(f * 16) * D_MODEL + k0, Bs + b * 8192 + f * 512 + l * 8);
  };

  // prologue: stage tiles 0 and 1 (4 loads each per wave)
  stage_unit(0, 0, 0); stage_unit(0, 1, 0);
  stage_unit(1, 0, 1); stage_unit(1, 1, 1);
  asm volatile("s_waitcnt vmcnt(4)" ::: "memory");   // tile 0 landed
  __builtin_amdgcn_sched_barrier(0);
  __builtin_amdgcn_s_barrier();
  __builtin_amdgcn_sched_barrier(0);

  for (int t = 0; t < 32; ++t) {                     // K = 1024 = 32 * 32
    const bf16* Ac = As + (t % 3) * 8192;
    const bf16* Bc = Bs + (t % 3) * 8192;
    const int bn = (t + 2) % 3;
    bf16x8 bfr[4];                                   // B-full, held across phases
#pragma unroll
    for (int p = 0; p < 2; ++p) {
      if (t + 2 < 32) stage_unit(t + 2, p, bn);
      if (p == 0) {
#pragma unroll
        for (int nt = 0; nt < 4; ++nt)
          bfr[nt] = *(const bf16x8*)&Bc[(wn * 4 + nt) * 512 + l * 8];
      }
      bf16x8 af[4];
#pragma unroll
      for (int j = 0; j < 4; ++j)
        af[j] = *(const bf16x8*)&Ac[(wm * 8 + p * 4 + j) * 512 + l * 8];
      __builtin_amdgcn_sched_barrier(0);
      __builtin_amdgcn_s_barrier();
      asm volatile("s_waitcnt lgkmcnt(0)" ::: "memory");
      __builtin_amdgcn_sched_barrier(0);
      __builtin_amdgcn_s_setprio(1);
#pragma unroll
      for (int j = 0; j < 4; ++j)
#pragma unroll
        for (int nt = 0; nt < 4; ++nt)
          acc[p * 4 + j][nt] = __builtin_amdgcn_mfma_f32_16x16x32_bf16(
              af[j], bfr[nt], acc[p * 4 + j][nt], 0, 0, 0);
      __builtin_amdgcn_s_setprio(0);
      __builtin_amdgcn_sched_barrier(0);
      if (p == 1) {
        if (t + 2 < 32)      asm volatile("s_waitcnt vmcnt(4)" ::: "memory");
        else if (t + 1 < 32) asm volatile("s_waitcnt vmcnt(0)" ::: "memory");
        __builtin_amdgcn_sched_barrier(0);
      }
      __builtin_amdgcn_s_barrier();
      __builtin_amdgcn_sched_barrier(0);
    }
  }
}

// ---------------- fused QKV projection GEMM ----------------
__global__ __launch_bounds__(512, 2)
void gemm_qkv(const bf16* __restrict__ A, const bf16* __restrict__ Bt,
              const float* __restrict__ bq, const float* __restrict__ bk,
              const float* __restrict__ bv,
              bf16* __restrict__ qo, bf16* __restrict__ ko, bf16* __restrict__ vto)
{
  __shared__ __attribute__((aligned(16))) bf16 As[24576];  // 3 x 16KB
  __shared__ __attribute__((aligned(16))) bf16 Bs[24576];
  const int tid = threadIdx.x;
  const int w = tid >> 6, l = tid & 63;
  const int ll = l & 15, lh = l >> 4;
  const int wm = w >> 2, wn = w & 3;

  const int idx = blockIdx.x;            // 0..767 = 8 xcd x 96
  const int xcd = idx & 7;
  const int local = idx >> 3;            // 0..95
  const int msub = local & 7;
  const int nblk = local >> 3;           // 0..11
  const int mblk = xcd * 8 + msub;       // 0..63
  const int m0 = mblk * 256, n0 = nblk * 256;

  floatx4 acc[8][4];
#pragma unroll
  for (int i = 0; i < 8; ++i)
#pragma unroll
    for (int j = 0; j < 4; ++j) acc[i][j] = (floatx4)0.f;

  gemm_core_3b(A, Bt, m0, n0, As, Bs, acc, w, l);

  const int sel = n0 >> 10;              // 0=q 1=k 2=v (block-uniform; 1024%256==0)
  const int ncl = n0 & 1023;
  const float* bias = (sel == 0) ? bq : (sel == 1) ? bk : bv;

#pragma unroll
  for (int mt = 0; mt < 8; ++mt) {
#pragma unroll
    for (int nt = 0; nt < 4; ++nt) {
      const int colL = ncl + wn * 64 + nt * 16 + ll;
      const float bvv = bias[colL];
#pragma unroll
      for (int r = 0; r < 4; ++r) {
        const int row = m0 + wm * 128 + mt * 16 + lh * 4 + r;
        const float v = acc[mt][nt][r] + bvv;
        if (sel == 0) {
          qo[(size_t)row * D_MODEL + colL] = (bf16)v;
        } else if (sel == 1) {
          ko[(size_t)row * D_MODEL + colL] = (bf16)v;
        } else {
          const int bb = row >> 12, s = row & 4095;
          vto[((size_t)bb * D_MODEL + colL) * SEQ + s] = (bf16)v;
        }
      }
    }
  }
}

// ---------------- output projection GEMM (fp32 out) ----------------
__global__ __launch_bounds__(512, 2)
void gemm_out(const bf16* __restrict__ A, const bf16* __restrict__ Bt,
              const float* __restrict__ bias, float* __restrict__ C)
{
  __shared__ __attribute__((aligned(16))) bf16 As[24576];
  __shared__ __attribute__((aligned(16))) bf16 Bs[24576];
  const int tid = threadIdx.x;
  const int w = tid >> 6, l = tid & 63;
  const int ll = l & 15, lh = l >> 4;
  const int wm = w >> 2, wn = w & 3;

  const int idx = blockIdx.x;            // 0..255 = 8 xcd x 32
  const int xcd = idx & 7;
  const int local = idx >> 3;            // 0..31
  const int msub = local & 7;
  const int nblk = local >> 3;           // 0..3
  const int mblk = xcd * 8 + msub;       // 0..63
  const int m0 = mblk * 256, n0 = nblk * 256;

  floatx4 acc[8][4];
#pragma unroll
  for (int i = 0; i < 8; ++i)
#pragma unroll
    for (int j = 0; j < 4; ++j) acc[i][j] = (floatx4)0.f;

  gemm_core_3b(A, Bt, m0, n0, As, Bs, acc, w, l);

#pragma unroll
  for (int mt = 0; mt < 8; ++mt) {
#pragma unroll
    for (int nt = 0; nt < 4; ++nt) {
      const int col = n0 + wn * 64 + nt * 16 + ll;
      const float bvv = bias[col];
#pragma unroll
      for (int r = 0; r < 4; ++r) {
        const int row = m0 + wm * 128 + mt * 16 + lh * 4 + r;
        C[(size_t)row * D_MODEL + col] = acc[mt][nt][r] + bvv;
      }
    }
  }
}

// ---------------- kernel A: QK^T + softmax -> normalized P (bf16) ----------------
// One block per (q-half, window, batch): 64 q rows x 128 keys, K=1024 contraction.
// Counted-vmcnt double-buffered staging (BK=64, vmcnt(6)).
__global__ __launch_bounds__(256)
void qk_softmax(const bf16* __restrict__ qb, const bf16* __restrict__ kb,
                bf16* __restrict__ Pg)
{
  __shared__ __attribute__((aligned(16))) bf16 As[8192];   // Q 2 x (64x64), 16KB
  __shared__ __attribute__((aligned(16))) bf16 Bs[16384];  // K 2 x (128x64), 32KB
  __shared__ float redM[4][64];
  __shared__ float redS[4][64];

  const int tid = threadIdx.x;
  const int w = tid >> 6, l = tid & 63, ll = l & 15, lh = l >> 4;
  const int wh = blockIdx.x;                 // 0..125
  const int win = wh >> 1, half = wh & 1;
  const int b = blockIdx.y;

  const bf16* Aq = qb + ((size_t)b * SEQ + win * 64 + half * 64) * D_MODEL
                 + (size_t)ll * D_MODEL + lh * 8;
  const bf16* Ak = kb + ((size_t)b * SEQ + win * 64) * D_MODEL
                 + (size_t)ll * D_MODEL + lh * 8;

  floatx4 acc[4][2];
#pragma unroll
  for (int i = 0; i < 4; ++i)
#pragma unroll
    for (int j = 0; j < 2; ++j) acc[i][j] = (floatx4)0.f;

  // stage: Q 2 issues + K 4 issues per thread per K-tile (BK=64)
  auto stage = [&](int t, int buf) {
    const int c0 = t << 6;
    bf16* Ad = As + buf * 4096;
    bf16* Bd = Bs + buf * 8192;
#pragma unroll
    for (int i = 0; i < 2; ++i) {            // Q: 8 frags (4 m x 2 kk)
      const int f = w * 2 + i;
      const int mt = f & 3, kk = f >> 2;
      async_ld16(Aq + (size_t)(mt * 16) * D_MODEL + (c0 + kk * 32),
                 Ad + f * 512 + l * 8);
    }
#pragma unroll
    for (int i = 0; i < 4; ++i) {            // K: 16 frags (8 n x 2 kk)
      const int f = w * 4 + i;
      const int mt = f & 7, kk = f >> 3;
      async_ld16(Ak + (size_t)(mt * 16) * D_MODEL + (c0 + kk * 32),
                 Bd + f * 512 + l * 8);
    }
  };

  stage(0, 0);
  stage(1, 1);

  for (int t = 0; t < 16; ++t) {
    if (t < 15) asm volatile("s_waitcnt vmcnt(6)" ::: "memory");
    else        asm volatile("s_waitcnt vmcnt(0)" ::: "memory");
    __builtin_amdgcn_s_barrier();
    __builtin_amdgcn_sched_barrier(0);
    const bf16* Ac = As + (t & 1) * 4096;
    const bf16* Bc = Bs + (t & 1) * 8192;
#pragma unroll
    for (int kk = 0; kk < 2; ++kk) {
      bf16x8 af[4], bfr[2];
#pragma unroll
      for (int tt = 0; tt < 4; ++tt)
        af[tt]  = *(const bf16x8*)&Ac[(kk * 4 + tt) * 512 + l * 8];
#pragma unroll
      for (int tt = 0; tt < 2; ++tt)
        bfr[tt] = *(const bf16x8*)&Bc[(kk * 8 + w * 2 + tt) * 512 + l * 8];
      __builtin_amdgcn_s_setprio(1);
#pragma unroll
      for (int mt = 0; mt < 4; ++mt)
#pragma unroll
        for (int nt = 0; nt < 2; ++nt)
          acc[mt][nt] = __builtin_amdgcn_mfma_f32_16x16x32_bf16(af[mt], bfr[nt], acc[mt][nt], 0, 0, 0);
      __builtin_amdgcn_s_setprio(0);
    }
    __builtin_amdgcn_sched_barrier(0);
    __builtin_amdgcn_s_barrier();
    __builtin_amdgcn_sched_barrier(0);
    if (t + 2 < 16) stage(t + 2, t & 1);
  }

  // scale by 1/sqrt(HEAD_DIM)=0.125
#pragma unroll
  for (int mt = 0; mt < 4; ++mt)
#pragma unroll
    for (int nt = 0; nt < 2; ++nt)
#pragma unroll
      for (int r = 0; r < 4; ++r) acc[mt][nt][r] *= 0.125f;

#pragma unroll
  for (int mt = 0; mt < 4; ++mt)
#pragma unroll
    for (int r = 0; r < 4; ++r) {
      float m = fmaxf(acc[mt][0][r], acc[mt][1][r]);
      m = fmaxf(m, __shfl_xor(m, 1));
      m = fmaxf(m, __shfl_xor(m, 2));
      m = fmaxf(m, __shfl_xor(m, 4));
      m = fmaxf(m, __shfl_xor(m, 8));
      if (ll == 0) redM[w][mt * 16 + lh * 4 + r] = m;
    }
  __syncthreads();

#pragma unroll
  for (int mt = 0; mt < 4; ++mt)
#pragma unroll
    for (int r = 0; r < 4; ++r) {
      const int row = mt * 16 + lh * 4 + r;
      const float m = fmaxf(fmaxf(redM[0][row], redM[1][row]),
                            fmaxf(redM[2][row], redM[3][row]));
      const float e0 = __expf(acc[mt][0][r] - m);
      const float e1 = __expf(acc[mt][1][r] - m);
      acc[mt][0][r] = e0; acc[mt][1][r] = e1;
      float s = e0 + e1;
      s += __shfl_xor(s, 1);
      s += __shfl_xor(s, 2);
      s += __shfl_xor(s, 4);
      s += __shfl_xor(s, 8);
      if (ll == 0) redS[w][row] = s;
    }
  __syncthreads();

  bf16* Pb = Pg + ((size_t)(b * NWIN + win) * 128 + half * 64) * 128;
#pragma unroll
  for (int mt = 0; mt < 4; ++mt)
#pragma unroll
    for (int r = 0; r < 4; ++r) {
      const int row = mt * 16 + lh * 4 + r;
      const float inv = 1.f / (redS[0][row] + redS[1][row] + redS[2][row] + redS[3][row]);
#pragma unroll
      for (int nt = 0; nt < 2; ++nt)
        Pb[(size_t)row * 128 + w * 32 + nt * 16 + ll] = (bf16)(acc[mt][nt][r] * inv);
    }
}

// ---------------- kernel B: gather-form P@V, averaged, direct bf16 store ----------
__global__ __launch_bounds__(256)
void pv_gather(const bf16* __restrict__ Pg, const bf16* __restrict__ vt,
               bf16* __restrict__ ab)
{
  __shared__ __attribute__((aligned(16))) bf16 As[4096];   // P 64x64, 8KB
  __shared__ __attribute__((aligned(16))) bf16 Bs[8192];   // Vt 128x64, 16KB

  const int tid = threadIdx.x;
  const int w = tid >> 6, l = tid & 63, ll = l & 15, lh = l >> 4;
  const int d0 = blockIdx.x * 128;           // 0..7
  const int h  = blockIdx.y;                 // 0..63
  const int b  = blockIdx.z;

  int wseg[2], roff[2];
  int nseg = 0;
  if (h >= 1)        { wseg[nseg] = h - 1; roff[nseg] = 64; ++nseg; }
  if (h <= NWIN - 1) { wseg[nseg] = h;     roff[nseg] = 0;  ++nseg; }
  const float scale = (nseg == 2) ? 0.5f : 1.0f;

  floatx4 acc[4][2];
#pragma unroll
  for (int i = 0; i < 4; ++i)
#pragma unroll
    for (int j = 0; j < 2; ++j) acc[i][j] = (floatx4)0.f;

  for (int sg = 0; sg < nseg; ++sg) {
    const bf16* Pseg = Pg + ((size_t)(b * NWIN + wseg[sg]) * 128 + roff[sg]) * 128;
    const bf16* Vseg = vt + ((size_t)b * D_MODEL + d0) * SEQ + wseg[sg] * 64;
    for (int c0 = 0; c0 < 128; c0 += 64) {
#pragma unroll
      for (int i = 0; i < 2; ++i) {          // P: 8 frags (4 m x 2 kk)
        const int f = w * 2 + i;
        const int mt = f & 3, kk = f >> 2;
        async_ld16(Pseg + (size_t)(mt * 16 + ll) * 128 + (c0 + kk * 32 + lh * 8),
                   &As[f * 512 + l * 8]);
      }
#pragma unroll
      for (int i = 0; i < 4; ++i) {          // Vt: 16 frags (8 n x 2 kk)
        const int f = w * 4 + i;
        const int mt = f & 7, kk = f >> 3;
        async_ld16(Vseg + (size_t)(mt * 16 + ll) * SEQ + (c0 + kk * 32 + lh * 8),
                   &Bs[f * 512 + l * 8]);
      }
      __syncthreads();
#pragma unroll
      for (int kk = 0; kk < 2; ++kk) {
        bf16x8 af[4], bfr[2];
#pragma unroll
        for (int t = 0; t < 4; ++t)
          af[t]  = *(const bf16x8*)&As[(kk * 4 + t) * 512 + l * 8];
#pragma unroll
        for (int t = 0; t < 2; ++t)
          bfr[t] = *(const bf16x8*)&Bs[(kk * 8 + w * 2 + t) * 512 + l * 8];
#pragma unroll
        for (int mt = 0; mt < 4; ++mt)
#pragma unroll
          for (int nt = 0; nt < 2; ++nt)
            acc[mt][nt] = __builtin_amdgcn_mfma_f32_16x16x32_bf16(af[mt], bfr[nt], acc[mt][nt], 0, 0, 0);
      }
      __syncthreads();
    }
  }

#pragma unroll
  for (int mt = 0; mt < 4; ++mt)
#pragma unroll
    for (int nt = 0; nt < 2; ++nt)
#pragma unroll
      for (int r = 0; r < 4; ++r) {
        const int row = h * 64 + mt * 16 + lh * 4 + r;
        const int col = d0 + w * 32 + nt * 16 + ll;
        ab[((size_t)b * SEQ + row) * D_MODEL + col] = (bf16)(acc[mt][nt][r] * scale);
      }
}

// ---------------- launcher ----------------
extern "C" void kernel_launch(void* const* d_in, const int* in_sizes, int n_in,
                              void* d_out, int out_size, void* d_ws, size_t ws_size,
                              hipStream_t stream)
{
  (void)in_sizes; (void)n_in; (void)out_size;

  const float* x  = (const float*)d_in[0];
  const float* Wq = (const float*)d_in[1];
  const float* bq = (const float*)d_in[2];
  const float* Wk = (const float*)d_in[3];
  const float* bk = (const float*)d_in[4];
  const float* Wv = (const float*)d_in[5];
  const float* bv = (const float*)d_in[6];
  const float* Wo = (const float*)d_in[7];
  const float* bo = (const float*)d_in[8];

  // workspace layout (bytes): xb 32M | wt 8M | qb 32M | kb 32M | vt 32M | ab 32M = 168 MiB
  // P (8.26 MB) aliases xb: xb's last use is gemm_qkv, P's first write is after.
  if (ws_size < (size_t)176160768) return;
  char* ws = (char*)d_ws;
  bf16* xb = (bf16*)(ws);
  bf16* pb = (bf16*)(ws);                  // P[b][win][128][128] bf16, aliases xb
  bf16* wt = (bf16*)(ws + 33554432);
  bf16* qb = (bf16*)(ws + 41943040);
  bf16* kb = (bf16*)(ws + 75497472);
  bf16* vt = (bf16*)(ws + 109051904);
  bf16* ab = (bf16*)(ws + 142606336);

  cvt_x_kernel<<<16384, 256, 0, stream>>>(x, xb);
  cvt_wt_kernel<<<dim3(32, 32, 4), 256, 0, stream>>>(Wq, Wk, Wv, Wo, wt);

  gemm_qkv<<<768, 512, 0, stream>>>(xb, wt, bq, bk, bv, qb, kb, vt);

  qk_softmax<<<dim3(126, BATCH), 256, 0, stream>>>(qb, kb, pb);
  pv_gather<<<dim3(8, 64, BATCH), 256, 0, stream>>>(pb, vt, ab);

  gemm_out<<<256, 512, 0, stream>>>(ab, wt + 3145728, bo, (float*)d_out);
}

// Round 5
// 433.855 us; speedup vs baseline: 1.1512x; 1.1512x over previous
//
#include <hip/hip_runtime.h>
#include <stdint.h>
#include <stddef.h>

#define D_MODEL 1024
#define SEQ     4096
#define BATCH   4
#define MTOT    (BATCH*SEQ)     // 16384
#define NWIN    63

typedef __bf16 bf16;
typedef __bf16 bf16x8 __attribute__((ext_vector_type(8)));
typedef __bf16 bf16x4 __attribute__((ext_vector_type(4)));
typedef float  floatx4 __attribute__((ext_vector_type(4)));

// async global->LDS, 16B per lane. LDS dest must be wave-uniform base + lane*16.
__device__ __forceinline__ void async_ld16(const void* g, void* l) {
  __builtin_amdgcn_global_load_lds(
      (const __attribute__((address_space(1))) unsigned int*)g,
      (__attribute__((address_space(3))) unsigned int*)l,
      16, 0, 0);
}

// ---------------- elementwise converts ----------------

__global__ __launch_bounds__(256)
void cvt_x_kernel(const float* __restrict__ x, bf16* __restrict__ xb)
{
  const int i = blockIdx.x * 256 + threadIdx.x;   // exactly 4M threads (16M elems /4)
  const float4 v = ((const float4*)x)[i];
  bf16x4 o = { (bf16)v.x, (bf16)v.y, (bf16)v.z, (bf16)v.w };
  ((bf16x4*)xb)[i] = o;
}

// W (fp32, [K][N]) -> Wt (bf16, [N][K]), packed: rows 0..1023=Wq^T, ..., 3072..4095=Wo^T
__global__ __launch_bounds__(256)
void cvt_wt_kernel(const float* __restrict__ W0, const float* __restrict__ W1,
                   const float* __restrict__ W2, const float* __restrict__ W3,
                   bf16* __restrict__ wt)
{
  __shared__ float tile[32][33];
  const float* Wsel = (blockIdx.z == 0) ? W0 : (blockIdx.z == 1) ? W1
                    : (blockIdx.z == 2) ? W2 : W3;
  bf16* Wt = wt + (size_t)blockIdx.z * D_MODEL * D_MODEL;
  const int tx = threadIdx.x & 31, ty = threadIdx.x >> 5;  // 32 x 8
  const int tn = blockIdx.x * 32, tk = blockIdx.y * 32;
#pragma unroll
  for (int j = 0; j < 32; j += 8)
    tile[ty + j][tx] = Wsel[(size_t)(tk + ty + j) * D_MODEL + (tn + tx)];
  __syncthreads();
#pragma unroll
  for (int j = 0; j < 32; j += 8)
    Wt[(size_t)(tn + ty + j) * D_MODEL + (tk + tx)] = (bf16)tile[tx][ty + j];
}

// ---------------- GEMM core: 256x256 tile, BK=64, coarse counted-vmcnt ----------
// 8 waves (2M x 4N), 512 threads. Per wave: 128x64 output = acc[8][4].
// LDS: A,B each 2 x 32KB double buffer (128KB total; 32 frags x 512 elem / buffer).
// R2's proven 2-barrier-per-tile structure at HALF the barrier density (BK 32->64):
//   vmcnt(8)             <- tile t's 8 loads landed; tile t+1's 8 stay IN FLIGHT
//   s_barrier            <- cross-wave: tile t fully resident
//   24 x ds_read_b128 (per kk-half: 12) ; 64 MFMA (compiler-interleaved)
//   s_barrier            <- all reads of buf[t&1] done
//   stage tile t+2 -> buf[t&1]  (8 loads; buffer just vacated)
// vmcnt never drains below 8 in steady state; prefetch depth 8-16 loads (~32-64KB).
// Frag-contiguous LDS layout is conflict-free (lane l reads frag*1KB + l*16B).
__device__ __forceinline__ void stage_tile64(const bf16* __restrict__ Ab,
                                             const bf16* __restrict__ Bb,
                                             bf16* As, bf16* Bs, int t, int buf,
                                             int w, int l)
{
  const int k0 = t << 6;
  bf16* Ad = As + buf * 16384;
  bf16* Bd = Bs + buf * 16384;
#pragma unroll
  for (int u = 0; u < 4; ++u) {
    const int f = u * 8 + w;                 // frag 0..31
    const int mt = f & 15, kk = f >> 4;      // row-block of 16, k-half of 32
    async_ld16(Ab + (size_t)(mt * 16) * D_MODEL + (k0 + kk * 32),
               Ad + f * 512 + l * 8);
    async_ld16(Bb + (size_t)(mt * 16) * D_MODEL + (k0 + kk * 32),
               Bd + f * 512 + l * 8);
  }
}

__device__ __forceinline__ void gemm_core_k64(const bf16* __restrict__ A,
                                              const bf16* __restrict__ Bt,
                                              int m0, int n0,
                                              bf16* As, bf16* Bs,
                                              floatx4 (&acc)[8][4],
                                              int w, int l)
{
  const int ll = l & 15, lh = l >> 4;
  const int wm = w >> 2, wn = w & 3;
  const bf16* Ab = A  + (size_t)(m0 + ll) * D_MODEL + lh * 8;
  const bf16* Bb = Bt + (size_t)(n0 + ll) * D_MODEL + lh * 8;

  stage_tile64(Ab, Bb, As, Bs, 0, 0, w, l);
  stage_tile64(Ab, Bb, As, Bs, 1, 1, w, l);

  for (int t = 0; t < 16; ++t) {             // K = 1024 = 16 * 64
    if (t < 15) asm volatile("s_waitcnt vmcnt(8)" ::: "memory");
    else        asm volatile("s_waitcnt vmcnt(0)" ::: "memory");
    __builtin_amdgcn_s_barrier();
    __builtin_amdgcn_sched_barrier(0);
    const bf16* Ac = As + (t & 1) * 16384;
    const bf16* Bc = Bs + (t & 1) * 16384;
#pragma unroll
    for (int kk = 0; kk < 2; ++kk) {
      bf16x8 af[8], bfr[4];
#pragma unroll
      for (int j = 0; j < 8; ++j)
        af[j] = *(const bf16x8*)&Ac[(kk * 16 + wm * 8 + j) * 512 + l * 8];
#pragma unroll
      for (int nt = 0; nt < 4; ++nt)
        bfr[nt] = *(const bf16x8*)&Bc[(kk * 16 + wn * 4 + nt) * 512 + l * 8];
      __builtin_amdgcn_s_setprio(1);
#pragma unroll
      for (int j = 0; j < 8; ++j)
#pragma unroll
        for (int nt = 0; nt < 4; ++nt)
          acc[j][nt] = __builtin_amdgcn_mfma_f32_16x16x32_bf16(af[j], bfr[nt], acc[j][nt], 0, 0, 0);
      __builtin_amdgcn_s_setprio(0);
    }
    __builtin_amdgcn_sched_barrier(0);
    __builtin_amdgcn_s_barrier();
    __builtin_amdgcn_sched_barrier(0);
    if (t + 2 < 16) stage_tile64(Ab, Bb, As, Bs, t + 2, t & 1, w, l);
  }
}

// ---------------- fused QKV projection GEMM ----------------
__global__ __launch_bounds__(512, 2)
void gemm_qkv(const bf16* __restrict__ A, const bf16* __restrict__ Bt,
              const float* __restrict__ bq, const float* __restrict__ bk,
              const float* __restrict__ bv,
              bf16* __restrict__ qo, bf16* __restrict__ ko, bf16* __restrict__ vto)
{
  __shared__ __attribute__((aligned(16))) bf16 As[32768];  // 2 x 32KB
  __shared__ __attribute__((aligned(16))) bf16 Bs[32768];
  const int tid = threadIdx.x;
  const int w = tid >> 6, l = tid & 63;
  const int ll = l & 15, lh = l >> 4;
  const int wm = w >> 2, wn = w & 3;

  const int idx = blockIdx.x;            // 0..767 = 8 xcd x 96
  const int xcd = idx & 7;
  const int local = idx >> 3;            // 0..95
  const int msub = local & 7;
  const int nblk = local >> 3;           // 0..11
  const int mblk = xcd * 8 + msub;       // 0..63
  const int m0 = mblk * 256, n0 = nblk * 256;

  floatx4 acc[8][4];
#pragma unroll
  for (int i = 0; i < 8; ++i)
#pragma unroll
    for (int j = 0; j < 4; ++j) acc[i][j] = (floatx4)0.f;

  gemm_core_k64(A, Bt, m0, n0, As, Bs, acc, w, l);

  const int sel = n0 >> 10;              // 0=q 1=k 2=v (block-uniform; 1024%256==0)
  const int ncl = n0 & 1023;
  const float* bias = (sel == 0) ? bq : (sel == 1) ? bk : bv;

#pragma unroll
  for (int mt = 0; mt < 8; ++mt) {
#pragma unroll
    for (int nt = 0; nt < 4; ++nt) {
      const int colL = ncl + wn * 64 + nt * 16 + ll;
      const float bvv = bias[colL];
#pragma unroll
      for (int r = 0; r < 4; ++r) {
        const int row = m0 + wm * 128 + mt * 16 + lh * 4 + r;
        const float v = acc[mt][nt][r] + bvv;
        if (sel == 0) {
          qo[(size_t)row * D_MODEL + colL] = (bf16)v;
        } else if (sel == 1) {
          ko[(size_t)row * D_MODEL + colL] = (bf16)v;
        } else {
          const int bb = row >> 12, s = row & 4095;
          vto[((size_t)bb * D_MODEL + colL) * SEQ + s] = (bf16)v;
        }
      }
    }
  }
}

// ---------------- output projection GEMM (fp32 out) ----------------
__global__ __launch_bounds__(512, 2)
void gemm_out(const bf16* __restrict__ A, const bf16* __restrict__ Bt,
              const float* __restrict__ bias, float* __restrict__ C)
{
  __shared__ __attribute__((aligned(16))) bf16 As[32768];
  __shared__ __attribute__((aligned(16))) bf16 Bs[32768];
  const int tid = threadIdx.x;
  const int w = tid >> 6, l = tid & 63;
  const int ll = l & 15, lh = l >> 4;
  const int wm = w >> 2, wn = w & 3;

  const int idx = blockIdx.x;            // 0..255 = 8 xcd x 32
  const int xcd = idx & 7;
  const int local = idx >> 3;            // 0..31
  const int msub = local & 7;
  const int nblk = local >> 3;           // 0..3
  const int mblk = xcd * 8 + msub;       // 0..63
  const int m0 = mblk * 256, n0 = nblk * 256;

  floatx4 acc[8][4];
#pragma unroll
  for (int i = 0; i < 8; ++i)
#pragma unroll
    for (int j = 0; j < 4; ++j) acc[i][j] = (floatx4)0.f;

  gemm_core_k64(A, Bt, m0, n0, As, Bs, acc, w, l);

#pragma unroll
  for (int mt = 0; mt < 8; ++mt) {
#pragma unroll
    for (int nt = 0; nt < 4; ++nt) {
      const int col = n0 + wn * 64 + nt * 16 + ll;
      const float bvv = bias[col];
#pragma unroll
      for (int r = 0; r < 4; ++r) {
        const int row = m0 + wm * 128 + mt * 16 + lh * 4 + r;
        C[(size_t)row * D_MODEL + col] = acc[mt][nt][r] + bvv;
      }
    }
  }
}

// ---------------- kernel A: QK^T + softmax -> normalized P (bf16) ----------------
// One block per (q-half, window, batch): 64 q rows x 128 keys, K=1024 contraction.
// Counted-vmcnt double-buffered staging (BK=64, vmcnt(6)).
__global__ __launch_bounds__(256)
void qk_softmax(const bf16* __restrict__ qb, const bf16* __restrict__ kb,
                bf16* __restrict__ Pg)
{
  __shared__ __attribute__((aligned(16))) bf16 As[8192];   // Q 2 x (64x64), 16KB
  __shared__ __attribute__((aligned(16))) bf16 Bs[16384];  // K 2 x (128x64), 32KB
  __shared__ float redM[4][64];
  __shared__ float redS[4][64];

  const int tid = threadIdx.x;
  const int w = tid >> 6, l = tid & 63, ll = l & 15, lh = l >> 4;
  const int wh = blockIdx.x;                 // 0..125
  const int win = wh >> 1, half = wh & 1;
  const int b = blockIdx.y;

  const bf16* Aq = qb + ((size_t)b * SEQ + win * 64 + half * 64) * D_MODEL
                 + (size_t)ll * D_MODEL + lh * 8;
  const bf16* Ak = kb + ((size_t)b * SEQ + win * 64) * D_MODEL
                 + (size_t)ll * D_MODEL + lh * 8;

  floatx4 acc[4][2];
#pragma unroll
  for (int i = 0; i < 4; ++i)
#pragma unroll
    for (int j = 0; j < 2; ++j) acc[i][j] = (floatx4)0.f;

  // stage: Q 2 issues + K 4 issues per thread per K-tile (BK=64)
  auto stage = [&](int t, int buf) {
    const int c0 = t << 6;
    bf16* Ad = As + buf * 4096;
    bf16* Bd = Bs + buf * 8192;
#pragma unroll
    for (int i = 0; i < 2; ++i) {            // Q: 8 frags (4 m x 2 kk)
      const int f = w * 2 + i;
      const int mt = f & 3, kk = f >> 2;
      async_ld16(Aq + (size_t)(mt * 16) * D_MODEL + (c0 + kk * 32),
                 Ad + f * 512 + l * 8);
    }
#pragma unroll
    for (int i = 0; i < 4; ++i) {            // K: 16 frags (8 n x 2 kk)
      const int f = w * 4 + i;
      const int mt = f & 7, kk = f >> 3;
      async_ld16(Ak + (size_t)(mt * 16) * D_MODEL + (c0 + kk * 32),
                 Bd + f * 512 + l * 8);
    }
  };

  stage(0, 0);
  stage(1, 1);

  for (int t = 0; t < 16; ++t) {
    if (t < 15) asm volatile("s_waitcnt vmcnt(6)" ::: "memory");
    else        asm volatile("s_waitcnt vmcnt(0)" ::: "memory");
    __builtin_amdgcn_s_barrier();
    __builtin_amdgcn_sched_barrier(0);
    const bf16* Ac = As + (t & 1) * 4096;
    const bf16* Bc = Bs + (t & 1) * 8192;
#pragma unroll
    for (int kk = 0; kk < 2; ++kk) {
      bf16x8 af[4], bfr[2];
#pragma unroll
      for (int tt = 0; tt < 4; ++tt)
        af[tt]  = *(const bf16x8*)&Ac[(kk * 4 + tt) * 512 + l * 8];
#pragma unroll
      for (int tt = 0; tt < 2; ++tt)
        bfr[tt] = *(const bf16x8*)&Bc[(kk * 8 + w * 2 + tt) * 512 + l * 8];
      __builtin_amdgcn_s_setprio(1);
#pragma unroll
      for (int mt = 0; mt < 4; ++mt)
#pragma unroll
        for (int nt = 0; nt < 2; ++nt)
          acc[mt][nt] = __builtin_amdgcn_mfma_f32_16x16x32_bf16(af[mt], bfr[nt], acc[mt][nt], 0, 0, 0);
      __builtin_amdgcn_s_setprio(0);
    }
    __builtin_amdgcn_sched_barrier(0);
    __builtin_amdgcn_s_barrier();
    __builtin_amdgcn_sched_barrier(0);
    if (t + 2 < 16) stage(t + 2, t & 1);
  }

  // scale by 1/sqrt(HEAD_DIM)=0.125
#pragma unroll
  for (int mt = 0; mt < 4; ++mt)
#pragma unroll
    for (int nt = 0; nt < 2; ++nt)
#pragma unroll
      for (int r = 0; r < 4; ++r) acc[mt][nt][r] *= 0.125f;

#pragma unroll
  for (int mt = 0; mt < 4; ++mt)
#pragma unroll
    for (int r = 0; r < 4; ++r) {
      float m = fmaxf(acc[mt][0][r], acc[mt][1][r]);
      m = fmaxf(m, __shfl_xor(m, 1));
      m = fmaxf(m, __shfl_xor(m, 2));
      m = fmaxf(m, __shfl_xor(m, 4));
      m = fmaxf(m, __shfl_xor(m, 8));
      if (ll == 0) redM[w][mt * 16 + lh * 4 + r] = m;
    }
  __syncthreads();

#pragma unroll
  for (int mt = 0; mt < 4; ++mt)
#pragma unroll
    for (int r = 0; r < 4; ++r) {
      const int row = mt * 16 + lh * 4 + r;
      const float m = fmaxf(fmaxf(redM[0][row], redM[1][row]),
                            fmaxf(redM[2][row], redM[3][row]));
      const float e0 = __expf(acc[mt][0][r] - m);
      const float e1 = __expf(acc[mt][1][r] - m);
      acc[mt][0][r] = e0; acc[mt][1][r] = e1;
      float s = e0 + e1;
      s += __shfl_xor(s, 1);
      s += __shfl_xor(s, 2);
      s += __shfl_xor(s, 4);
      s += __shfl_xor(s, 8);
      if (ll == 0) redS[w][row] = s;
    }
  __syncthreads();

  bf16* Pb = Pg + ((size_t)(b * NWIN + win) * 128 + half * 64) * 128;
#pragma unroll
  for (int mt = 0; mt < 4; ++mt)
#pragma unroll
    for (int r = 0; r < 4; ++r) {
      const int row = mt * 16 + lh * 4 + r;
      const float inv = 1.f / (redS[0][row] + redS[1][row] + redS[2][row] + redS[3][row]);
#pragma unroll
      for (int nt = 0; nt < 2; ++nt)
        Pb[(size_t)row * 128 + w * 32 + nt * 16 + ll] = (bf16)(acc[mt][nt][r] * inv);
    }
}

// ---------------- kernel B: gather-form P@V, averaged, direct bf16 store ----------
__global__ __launch_bounds__(256)
void pv_gather(const bf16* __restrict__ Pg, const bf16* __restrict__ vt,
               bf16* __restrict__ ab)
{
  __shared__ __attribute__((aligned(16))) bf16 As[4096];   // P 64x64, 8KB
  __shared__ __attribute__((aligned(16))) bf16 Bs[8192];   // Vt 128x64, 16KB

  const int tid = threadIdx.x;
  const int w = tid >> 6, l = tid & 63, ll = l & 15, lh = l >> 4;
  const int d0 = blockIdx.x * 128;           // 0..7
  const int h  = blockIdx.y;                 // 0..63
  const int b  = blockIdx.z;

  int wseg[2], roff[2];
  int nseg = 0;
  if (h >= 1)        { wseg[nseg] = h - 1; roff[nseg] = 64; ++nseg; }
  if (h <= NWIN - 1) { wseg[nseg] = h;     roff[nseg] = 0;  ++nseg; }
  const float scale = (nseg == 2) ? 0.5f : 1.0f;

  floatx4 acc[4][2];
#pragma unroll
  for (int i = 0; i < 4; ++i)
#pragma unroll
    for (int j = 0; j < 2; ++j) acc[i][j] = (floatx4)0.f;

  for (int sg = 0; sg < nseg; ++sg) {
    const bf16* Pseg = Pg + ((size_t)(b * NWIN + wseg[sg]) * 128 + roff[sg]) * 128;
    const bf16* Vseg = vt + ((size_t)b * D_MODEL + d0) * SEQ + wseg[sg] * 64;
    for (int c0 = 0; c0 < 128; c0 += 64) {
#pragma unroll
      for (int i = 0; i < 2; ++i) {          // P: 8 frags (4 m x 2 kk)
        const int f = w * 2 + i;
        const int mt = f & 3, kk = f >> 2;
        async_ld16(Pseg + (size_t)(mt * 16 + ll) * 128 + (c0 + kk * 32 + lh * 8),
                   &As[f * 512 + l * 8]);
      }
#pragma unroll
      for (int i = 0; i < 4; ++i) {          // Vt: 16 frags (8 n x 2 kk)
        const int f = w * 4 + i;
        const int mt = f & 7, kk = f >> 3;
        async_ld16(Vseg + (size_t)(mt * 16 + ll) * SEQ + (c0 + kk * 32 + lh * 8),
                   &Bs[f * 512 + l * 8]);
      }
      __syncthreads();
#pragma unroll
      for (int kk = 0; kk < 2; ++kk) {
        bf16x8 af[4], bfr[2];
#pragma unroll
        for (int t = 0; t < 4; ++t)
          af[t]  = *(const bf16x8*)&As[(kk * 4 + t) * 512 + l * 8];
#pragma unroll
        for (int t = 0; t < 2; ++t)
          bfr[t] = *(const bf16x8*)&Bs[(kk * 8 + w * 2 + t) * 512 + l * 8];
#pragma unroll
        for (int mt = 0; mt < 4; ++mt)
#pragma unroll
          for (int nt = 0; nt < 2; ++nt)
            acc[mt][nt] = __builtin_amdgcn_mfma_f32_16x16x32_bf16(af[mt], bfr[nt], acc[mt][nt], 0, 0, 0);
      }
      __syncthreads();
    }
  }

#pragma unroll
  for (int mt = 0; mt < 4; ++mt)
#pragma unroll
    for (int nt = 0; nt < 2; ++nt)
#pragma unroll
      for (int r = 0; r < 4; ++r) {
        const int row = h * 64 + mt * 16 + lh * 4 + r;
        const int col = d0 + w * 32 + nt * 16 + ll;
        ab[((size_t)b * SEQ + row) * D_MODEL + col] = (bf16)(acc[mt][nt][r] * scale);
      }
}

// ---------------- launcher ----------------
extern "C" void kernel_launch(void* const* d_in, const int* in_sizes, int n_in,
                              void* d_out, int out_size, void* d_ws, size_t ws_size,
                              hipStream_t stream)
{
  (void)in_sizes; (void)n_in; (void)out_size;

  const float* x  = (const float*)d_in[0];
  const float* Wq = (const float*)d_in[1];
  const float* bq = (const float*)d_in[2];
  const float* Wk = (const float*)d_in[3];
  const float* bk = (const float*)d_in[4];
  const float* Wv = (const float*)d_in[5];
  const float* bv = (const float*)d_in[6];
  const float* Wo = (const float*)d_in[7];
  const float* bo = (const float*)d_in[8];

  // workspace layout (bytes): xb 32M | wt 8M | qb 32M | kb 32M | vt 32M | ab 32M = 168 MiB
  // P (8.26 MB) aliases xb: xb's last use is gemm_qkv, P's first write is after.
  if (ws_size < (size_t)176160768) return;
  char* ws = (char*)d_ws;
  bf16* xb = (bf16*)(ws);
  bf16* pb = (bf16*)(ws);                  // P[b][win][128][128] bf16, aliases xb
  bf16* wt = (bf16*)(ws + 33554432);
  bf16* qb = (bf16*)(ws + 41943040);
  bf16* kb = (bf16*)(ws + 75497472);
  bf16* vt = (bf16*)(ws + 109051904);
  bf16* ab = (bf16*)(ws + 142606336);

  cvt_x_kernel<<<16384, 256, 0, stream>>>(x, xb);
  cvt_wt_kernel<<<dim3(32, 32, 4), 256, 0, stream>>>(Wq, Wk, Wv, Wo, wt);

  gemm_qkv<<<768, 512, 0, stream>>>(xb, wt, bq, bk, bv, qb, kb, vt);

  qk_softmax<<<dim3(126, BATCH), 256, 0, stream>>>(qb, kb, pb);
  pv_gather<<<dim3(8, 64, BATCH), 256, 0, stream>>>(pb, vt, ab);

  gemm_out<<<256, 512, 0, stream>>>(ab, wt + 3145728, bo, (float*)d_out);
}